// Round 3
// baseline (113.588 us; speedup 1.0000x reference)
//
#include <hip/hip_runtime.h>
#include <hip/hip_fp16.h>

#define NQ 2048
#define NK 4096
#define DIMK 1024
#define HD 256          // 2*H*D_I
#define NBUCKET 257

typedef _Float16 h2 __attribute__((ext_vector_type(2)));
typedef _Float16 h4 __attribute__((ext_vector_type(4)));
typedef float f4 __attribute__((ext_vector_type(4)));

// async global->LDS, 16B per lane (size must be a literal)
#define GLDS16(gp, lp)                                              \
  __builtin_amdgcn_global_load_lds(                                 \
      (const __attribute__((address_space(1))) void*)(gp),          \
      (__attribute__((address_space(3))) void*)(lp), 16, 0, 0)

// ---------------------------------------------------------------------------
// Kernel 1: fused f32->f16 projection GEMM  P = X @ W^T  (f16 out)
// (unchanged from round 2)
// ---------------------------------------------------------------------------
__global__ __launch_bounds__(256) void proj_kernel(
    const float* __restrict__ Xq, const float* __restrict__ Xk,
    const float* __restrict__ Wq, const float* __restrict__ Wk,
    _Float16* __restrict__ Pq, _Float16* __restrict__ Pk)
{
  __shared__ __align__(16) float xs[2][32 * 64];   // 2 x 8 KB
  __shared__ __align__(16) float wsh[2][64 * 64];  // 2 x 16 KB  -> 48 KB total

  const int t = threadIdx.x;
  const int lane = t & 63;
  const int wave = t >> 6;
  const int bx = blockIdx.x;
  const bool isq = bx < (NQ / 32);
  const float* __restrict__ X = isq ? Xq : Xk;
  const float* __restrict__ W = isq ? Wq : Wk;
  _Float16* __restrict__ P = isq ? Pq : Pk;
  const int rb = (isq ? bx : bx - NQ / 32) * 32;
  const int cb = blockIdx.y * 64;
  const int r15 = lane & 15, g = lane >> 4;
  const int wq = wave >> 1, wk = wave & 1;
  const int c4 = t & 15;  // this thread's 16B chunk within a 64-float row

  f4 acc[2];
  acc[0] = (f4){0.f, 0.f, 0.f, 0.f};
  acc[1] = (f4){0.f, 0.f, 0.f, 0.f};

  auto stage = [&](int buf, int kb) {
#pragma unroll
    for (int c = 0; c < 2; ++c) {
      int flat = c * 1024 + t * 4;          // float index in 32x64 tile
      int row = flat >> 6;
      int gc = c4 ^ (row & 7);              // pre-swizzled source chunk
      GLDS16(X + (size_t)(rb + row) * DIMK + kb + gc * 4, &xs[buf][flat]);
    }
#pragma unroll
    for (int c = 0; c < 4; ++c) {
      int flat = c * 1024 + t * 4;          // float index in 64x64 tile
      int row = flat >> 6;
      int gc = c4 ^ (row & 7);
      GLDS16(W + (size_t)(cb + row) * DIMK + kb + gc * 4, &wsh[buf][flat]);
    }
  };

  auto compute = [&](int buf) {
    const int arow = wq * 16 + r15;
#pragma unroll
    for (int kc = 0; kc < 4; ++kc) {
      int k4 = kc * 4 + g;                  // 16B chunk holding this frag's 4 halves
      f4 af = *(const f4*)&xs[buf][arow * 64 + ((k4 ^ (arow & 7)) << 2)];
      h4 a;
      a[0] = (_Float16)af[0]; a[1] = (_Float16)af[1];
      a[2] = (_Float16)af[2]; a[3] = (_Float16)af[3];
#pragma unroll
      for (int cs = 0; cs < 2; ++cs) {
        int brow = wk * 32 + cs * 16 + r15;
        f4 bf = *(const f4*)&wsh[buf][brow * 64 + ((k4 ^ (brow & 7)) << 2)];
        h4 b;
        b[0] = (_Float16)bf[0]; b[1] = (_Float16)bf[1];
        b[2] = (_Float16)bf[2]; b[3] = (_Float16)bf[3];
        acc[cs] = __builtin_amdgcn_mfma_f32_16x16x16f16(a, b, acc[cs], 0, 0, 0);
      }
    }
  };

  stage(0, 0);
  __syncthreads();
  int buf = 0;
  for (int tt = 0; tt < DIMK / 64; ++tt) {
    if (tt + 1 < DIMK / 64) stage(buf ^ 1, (tt + 1) * 64);
    compute(buf);
    __syncthreads();
    buf ^= 1;
  }

#pragma unroll
  for (int cs = 0; cs < 2; ++cs)
#pragma unroll
    for (int i = 0; i < 4; ++i)
      P[(size_t)(rb + wq * 16 + g * 4 + i) * HD + cb + wk * 32 + cs * 16 + r15] =
          (_Float16)acc[cs][i];
}

// ---------------------------------------------------------------------------
// Kernel 2 (v2): no q/k LDS staging. A-strip register-resident, B streamed
// from global (L1/L2-served). Gate MLP in packed f16, sigmoid via v_exp.
// Block tile: 32 q x 64 k; 4 waves (wq 2 x wk 2), wave tile 16q x 32k,
// split into two 16x16 k-subtiles (s) to halve accumulator live range.
// grid = (NK/64, NQ/32). LDS = rpe table only (~4 KB).
// ---------------------------------------------------------------------------
__global__ __launch_bounds__(256, 4) void fused_kernel(
    const _Float16* __restrict__ qp, const _Float16* __restrict__ kp,
    const int* __restrict__ qpos, const int* __restrict__ kpos,
    const float* __restrict__ rpe, const float* __restrict__ gw1,
    const float* __restrict__ gb1, const float* __restrict__ gw2,
    const float* __restrict__ gb2, float* __restrict__ out)
{
  __shared__ __align__(16) float rpel[NBUCKET * 4];

  const int t = threadIdx.x;
  const int lane = t & 63, wave = t >> 6;
  const int wq = wave >> 1, wk = wave & 1;
  const int qb = blockIdx.y * 32, kb = blockIdx.x * 64;
  const int r15 = lane & 15, g = lane >> 4;

  for (int i = t; i < NBUCKET * 4; i += 256) rpel[i] = rpe[i];
  __syncthreads();

  // ---- A fragments (this wave's 16 q-rows) held in registers ----
  const int qrow = qb + wq * 16 + r15;
  const _Float16* qbase = qp + (size_t)qrow * HD + g * 4;
  h4 afr[8][2];
#pragma unroll
  for (int h = 0; h < 8; ++h)
#pragma unroll
    for (int c = 0; c < 2; ++c)
      afr[h][c] = *(const h4*)(qbase + h * 32 + c * 16);

  // ---- packed-f16 gate weights (uniform; converted once) ----
  h2 w1p[4][4], b1p[4];          // layer1: [h][jpair over hidden]
  h2 w2p[8][2], b2p[2];          // layer2: [e][jpair over heads]
#pragma unroll
  for (int j = 0; j < 4; ++j) {
    b1p[j] = (h2){(_Float16)gb1[2 * j], (_Float16)gb1[2 * j + 1]};
#pragma unroll
    for (int h = 0; h < 4; ++h)
      w1p[h][j] = (h2){(_Float16)gw1[(2 * j) * 4 + h],
                       (_Float16)gw1[(2 * j + 1) * 4 + h]};
  }
#pragma unroll
  for (int j = 0; j < 2; ++j)
    b2p[j] = (h2){(_Float16)gb2[2 * j], (_Float16)gb2[2 * j + 1]};
#pragma unroll
  for (int e = 0; e < 8; ++e)
#pragma unroll
    for (int j = 0; j < 2; ++j)
      w2p[e][j] = (h2){(_Float16)gw2[(2 * j) * 8 + e],
                       (_Float16)gw2[(2 * j + 1) * 8 + e]};

  const int4 qp4 = *(const int4*)(qpos + qb + wq * 16 + g * 4);

#pragma unroll
  for (int s = 0; s < 2; ++s) {
    const int krow = kb + wk * 32 + s * 16 + r15;
    const _Float16* kbase = kp + (size_t)krow * HD + g * 4;

    f4 acc[8];
#pragma unroll
    for (int h = 0; h < 8; ++h) acc[h] = (f4){0.f, 0.f, 0.f, 0.f};
#pragma unroll
    for (int h = 0; h < 8; ++h)
#pragma unroll
      for (int c = 0; c < 2; ++c) {
        h4 b = *(const h4*)(kbase + h * 32 + c * 16);
        acc[h] = __builtin_amdgcn_mfma_f32_16x16x16f16(afr[h][c], b, acc[h], 0, 0, 0);
      }

    const int kpv = kpos[krow];
#pragma unroll
    for (int i = 0; i < 4; ++i) {
      int rel = qp4[i] - kpv;
      int bidx = (rel < -128 ? -128 : (rel > 128 ? 128 : rel)) + 128;
      f4 rp = *(const f4*)&rpel[bidx * 4];

      // gate input, packed to f16
      h2 gi01 = (h2){(_Float16)(acc[4][i] + rp[0]), (_Float16)(acc[5][i] + rp[1])};
      h2 gi23 = (h2){(_Float16)(acc[6][i] + rp[2]), (_Float16)(acc[7][i] + rp[3])};

      // layer 1: hidden = relu(W1 @ gi + b1), 4 x h2
      h2 hid[4];
#pragma unroll
      for (int j = 0; j < 4; ++j) {
        h2 a = b1p[j];
        a += (h2){gi01[0], gi01[0]} * w1p[0][j];
        a += (h2){gi01[1], gi01[1]} * w1p[1][j];
        a += (h2){gi23[0], gi23[0]} * w1p[2][j];
        a += (h2){gi23[1], gi23[1]} * w1p[3][j];
        hid[j] = __builtin_elementwise_max(a, (h2)(_Float16)0.0f);
      }
      // layer 2: gs = W2 @ hidden + b2, 2 x h2
      h2 gs0 = b2p[0], gs1 = b2p[1];
#pragma unroll
      for (int e = 0; e < 8; ++e) {
        h2 he = (h2){hid[e >> 1][e & 1], hid[e >> 1][e & 1]};
        gs0 += he * w2p[e][0];
        gs1 += he * w2p[e][1];
      }

      float ov = 0.0f;
#pragma unroll
      for (int h = 0; h < 4; ++h) {
        float gsf = (float)((h < 2 ? gs0 : gs1)[h & 1]);
        float sd = fmaxf(acc[h][i] + rp[h], 0.0f);
        float e2 = __builtin_amdgcn_exp2f(gsf * -1.44269504f);
        ov += sd * __builtin_amdgcn_rcpf(1.0f + e2);
      }
      out[(size_t)(qb + wq * 16 + g * 4 + i) * NK + krow] = ov;
    }
  }
}

// ---------------------------------------------------------------------------
extern "C" void kernel_launch(void* const* d_in, const int* in_sizes, int n_in,
                              void* d_out, int out_size, void* d_ws, size_t ws_size,
                              hipStream_t stream) {
  const float* Xq  = (const float*)d_in[0];
  const float* Xk  = (const float*)d_in[1];
  const int*   qpos = (const int*)d_in[2];
  const int*   kpos = (const int*)d_in[3];
  const float* Wq  = (const float*)d_in[4];
  const float* Wk  = (const float*)d_in[5];
  const float* rpe = (const float*)d_in[6];
  const float* gw1 = (const float*)d_in[7];
  const float* gb1 = (const float*)d_in[8];
  const float* gw2 = (const float*)d_in[9];
  const float* gb2 = (const float*)d_in[10];
  float* out = (float*)d_out;

  _Float16* qpf = (_Float16*)d_ws;                 // 2048*256 f16 = 1 MB
  _Float16* kpf = qpf + (size_t)NQ * HD;           // 4096*256 f16 = 2 MB

  proj_kernel<<<dim3(NQ / 32 + NK / 32, 4), 256, 0, stream>>>(
      Xq, Xk, Wq, Wk, qpf, kpf);
  fused_kernel<<<dim3(NK / 64, NQ / 32), 256, 0, stream>>>(
      qpf, kpf, qpos, kpos, rpe, gw1, gb1, gw2, gb2, out);
}

// Round 5
// 73.388 us; speedup vs baseline: 1.5478x; 1.5478x over previous
//
#include <hip/hip_runtime.h>
#include <hip/hip_fp16.h>

#define NQ 2048
#define NK 4096
#define DIMK 1024
#define HD 256          // 2*H*D_I
#define NBUCKET 257

typedef _Float16 h2 __attribute__((ext_vector_type(2)));
typedef _Float16 h4 __attribute__((ext_vector_type(4)));
typedef float f4 __attribute__((ext_vector_type(4)));

// v_cvt_pkrtz_f16_f32: pack two f32 into one f16x2 (bit-cast to our h2)
static __device__ __forceinline__ h2 cvt_pk(float a, float b) {
  return __builtin_bit_cast(h2, __builtin_amdgcn_cvt_pkrtz(a, b));
}

// async global->LDS, 16B per lane (size must be a literal)
#define GLDS16(gp, lp)                                              \
  __builtin_amdgcn_global_load_lds(                                 \
      (const __attribute__((address_space(1))) void*)(gp),          \
      (__attribute__((address_space(3))) void*)(lp), 16, 0, 0)

// ---------------------------------------------------------------------------
// Kernel 1: fused f32->f16 projection GEMM  P = X @ W^T  (f16 out)
// Block tile 32(rows) x 32(cols), BK=64, 4 waves (2x2), wave tile 16x16.
// LDS 32 KB (double-buffered) -> 5 blocks/CU. global_load_lds staging with
// source-side XOR swizzle (16B chunk ^= row&7); same XOR on ds_read_b128.
// Grid.x = NQ/32 + NK/32 = 192, grid.y = 256/32 = 8.
// ---------------------------------------------------------------------------
__global__ __launch_bounds__(256, 5) void proj_kernel(
    const float* __restrict__ Xq, const float* __restrict__ Xk,
    const float* __restrict__ Wq, const float* __restrict__ Wk,
    _Float16* __restrict__ Pq, _Float16* __restrict__ Pk)
{
  __shared__ __align__(16) float xs[2][32 * 64];   // 2 x 8 KB
  __shared__ __align__(16) float wsh[2][32 * 64];  // 2 x 8 KB -> 32 KB total

  const int t = threadIdx.x;
  const int lane = t & 63;
  const int wave = t >> 6;
  const int bx = blockIdx.x;
  const bool isq = bx < (NQ / 32);
  const float* __restrict__ X = isq ? Xq : Xk;
  const float* __restrict__ W = isq ? Wq : Wk;
  _Float16* __restrict__ P = isq ? Pq : Pk;
  const int rb = (isq ? bx : bx - NQ / 32) * 32;
  const int cb = blockIdx.y * 32;
  const int r15 = lane & 15, g = lane >> 4;
  const int wq = wave >> 1, wk = wave & 1;

  f4 acc = (f4){0.f, 0.f, 0.f, 0.f};

  // stage one K-tile: X 2 calls + W 2 calls (each 256 lanes x 16B)
  auto stage = [&](int buf, int kb) {
#pragma unroll
    for (int j = 0; j < 2; ++j) {
      int chunk = j * 256 + t;              // 16B chunk in 32x64-float tile
      int row = chunk >> 4, c4 = chunk & 15;
      int gc = c4 ^ (row & 7);              // inverse-swizzled source chunk
      GLDS16(X + (size_t)(rb + row) * DIMK + kb + gc * 4, &xs[buf][chunk * 4]);
    }
#pragma unroll
    for (int j = 0; j < 2; ++j) {
      int chunk = j * 256 + t;
      int row = chunk >> 4, c4 = chunk & 15;
      int gc = c4 ^ (row & 7);
      GLDS16(W + (size_t)(cb + row) * DIMK + kb + gc * 4, &wsh[buf][chunk * 4]);
    }
  };

  auto compute = [&](int buf) {
    const int arow = wq * 16 + r15;
    const int brow = wk * 16 + r15;
#pragma unroll
    for (int kc = 0; kc < 4; ++kc) {
      int k4 = kc * 4 + g;                  // 16B chunk holding this frag's 4 vals
      f4 af = *(const f4*)&xs[buf][arow * 64 + ((k4 ^ (arow & 7)) << 2)];
      h2 alo = cvt_pk(af[0], af[1]);
      h2 ahi = cvt_pk(af[2], af[3]);
      h4 a = (h4){alo[0], alo[1], ahi[0], ahi[1]};
      f4 bf = *(const f4*)&wsh[buf][brow * 64 + ((k4 ^ (brow & 7)) << 2)];
      h2 blo = cvt_pk(bf[0], bf[1]);
      h2 bhi = cvt_pk(bf[2], bf[3]);
      h4 b = (h4){blo[0], blo[1], bhi[0], bhi[1]};
      acc = __builtin_amdgcn_mfma_f32_16x16x16f16(a, b, acc, 0, 0, 0);
    }
  };

  stage(0, 0);
  __syncthreads();
  int buf = 0;
  for (int tt = 0; tt < DIMK / 64; ++tt) {
    if (tt + 1 < DIMK / 64) stage(buf ^ 1, (tt + 1) * 64);
    compute(buf);
    __syncthreads();
    buf ^= 1;
  }

  // C/D layout: row = 4*(lane>>4)+i, col = lane&15  [measured m89]
#pragma unroll
  for (int i = 0; i < 4; ++i)
    P[(size_t)(rb + wq * 16 + g * 4 + i) * HD + cb + wk * 16 + r15] =
        (_Float16)acc[i];
}

// ---------------------------------------------------------------------------
// Kernel 2 (v3): LDS-staged tiles via global_load_lds (swizzled source),
// RPE pre-loaded into MFMA accumulator, packed-f16 gate MLP (no splat
// layer-2), sigmoid via exp2+rcp. Block 32q x 64k, 4 waves (2x2), wave
// 16q x 32k as two 16x16 k-subtiles. grid = (NK/64, NQ/32).
// ---------------------------------------------------------------------------
__global__ __launch_bounds__(256, 3) void fused_kernel(
    const _Float16* __restrict__ qp, const _Float16* __restrict__ kp,
    const int* __restrict__ qpos, const int* __restrict__ kpos,
    const float* __restrict__ rpe, const float* __restrict__ gw1,
    const float* __restrict__ gb1, const float* __restrict__ gw2,
    const float* __restrict__ gb2, float* __restrict__ out)
{
  __shared__ __align__(16) _Float16 qlds[32 * 256];   // 16 KB
  __shared__ __align__(16) _Float16 klds[64 * 256];   // 32 KB
  __shared__ __align__(16) float rpel[NBUCKET * 4];   // 4112 B
  __shared__ int qposl[32];
  __shared__ int kposl[64];

  const int t = threadIdx.x;
  const int lane = t & 63, wave = t >> 6;
  const int wq = wave >> 1, wk = wave & 1;
  const int qb = blockIdx.y * 32, kb = blockIdx.x * 64;
  const int r15 = lane & 15, g = lane >> 4;

  // stage q tile: 32 rows x 256 halfs; 16B chunks; source pre-swizzled so
  // LDS half index = colh ^ ((row&7)<<3)
#pragma unroll
  for (int j = 0; j < 4; ++j) {
    int chunk = j * 256 + t;
    int row = chunk >> 5, c = chunk & 31;
    GLDS16(qp + (size_t)(qb + row) * HD + (c ^ (row & 7)) * 8, &qlds[chunk * 8]);
  }
  // stage k tile: 64 rows
#pragma unroll
  for (int j = 0; j < 8; ++j) {
    int chunk = j * 256 + t;
    int row = chunk >> 5, c = chunk & 31;
    GLDS16(kp + (size_t)(kb + row) * HD + (c ^ (row & 7)) * 8, &klds[chunk * 8]);
  }
  for (int i = t; i < NBUCKET * 4; i += 256) rpel[i] = rpe[i];
  if (t < 32) qposl[t] = qpos[qb + t];
  else if (t < 96) kposl[t - 32] = kpos[kb + t - 32];
  __syncthreads();

  // ---- A fragments (this wave's 16 q-rows) from LDS ----
  const int qrow = wq * 16 + r15;
  const int swz = (r15 & 7) << 3;   // half-index XOR for this lane's rows
  h4 afr[8][2];
#pragma unroll
  for (int h = 0; h < 8; ++h)
#pragma unroll
    for (int c = 0; c < 2; ++c)
      afr[h][c] = *(const h4*)&qlds[qrow * 256 + ((h * 32 + c * 16 + g * 4) ^ swz)];

  // ---- packed-f16 gate weights (wave-uniform) ----
  h2 w1p[4][4], b1p[4];     // layer1: [head][hidden-pair]
  h2 w2hp[4][4];            // layer2: [head][hidden-pair]
  float b2f[4];
#pragma unroll
  for (int j = 0; j < 4; ++j) {
    b1p[j] = (h2){(_Float16)gb1[2 * j], (_Float16)gb1[2 * j + 1]};
#pragma unroll
    for (int h = 0; h < 4; ++h)
      w1p[h][j] = (h2){(_Float16)gw1[(2 * j) * 4 + h],
                       (_Float16)gw1[(2 * j + 1) * 4 + h]};
  }
#pragma unroll
  for (int h = 0; h < 4; ++h) {
    b2f[h] = gb2[h];
#pragma unroll
    for (int j = 0; j < 4; ++j)
      w2hp[h][j] = (h2){(_Float16)gw2[h * 8 + 2 * j],
                        (_Float16)gw2[h * 8 + 2 * j + 1]};
  }

  const int4 qp4 = *(const int4*)&qposl[wq * 16 + g * 4];

#pragma unroll
  for (int s = 0; s < 2; ++s) {
    const int krl = wk * 32 + s * 16 + r15;   // k row within tile
    const int kpv = kposl[krl];

    // rpe gather for this lane's 4 output elements; preload into accumulator
    f4 rpv[4];
#pragma unroll
    for (int i = 0; i < 4; ++i) {
      int rel = qp4[i] - kpv;
      int bidx = (rel < -128 ? -128 : (rel > 128 ? 128 : rel)) + 128;
      rpv[i] = *(const f4*)&rpel[bidx * 4];
    }
    f4 acc[8];
#pragma unroll
    for (int h = 0; h < 8; ++h)
#pragma unroll
      for (int i = 0; i < 4; ++i) acc[h][i] = rpv[i][h & 3];

#pragma unroll
    for (int h = 0; h < 8; ++h)
#pragma unroll
      for (int c = 0; c < 2; ++c) {
        h4 b = *(const h4*)&klds[krl * 256 + ((h * 32 + c * 16 + g * 4) ^ swz)];
        acc[h] = __builtin_amdgcn_mfma_f32_16x16x16f16(afr[h][c], b, acc[h], 0, 0, 0);
      }

#pragma unroll
    for (int i = 0; i < 4; ++i) {
      // gate input (already includes rpe), packed to f16
      h2 gi01 = cvt_pk(acc[4][i], acc[5][i]);
      h2 gi23 = cvt_pk(acc[6][i], acc[7][i]);
      h2 s0 = __builtin_shufflevector(gi01, gi01, 0, 0);
      h2 s1 = __builtin_shufflevector(gi01, gi01, 1, 1);
      h2 s2 = __builtin_shufflevector(gi23, gi23, 0, 0);
      h2 s3 = __builtin_shufflevector(gi23, gi23, 1, 1);

      // layer 1: hidden pairs
      h2 hidp[4];
#pragma unroll
      for (int j = 0; j < 4; ++j) {
        h2 a = b1p[j];
        a += s0 * w1p[0][j];
        a += s1 * w1p[1][j];
        a += s2 * w1p[2][j];
        a += s3 * w1p[3][j];
        hidp[j] = __builtin_elementwise_max(a, (h2)(_Float16)0.0f);
      }

      float ov = 0.0f;
#pragma unroll
      for (int h = 0; h < 4; ++h) {
        h2 g2 = hidp[0] * w2hp[h][0];
        g2 += hidp[1] * w2hp[h][1];
        g2 += hidp[2] * w2hp[h][2];
        g2 += hidp[3] * w2hp[h][3];
        float gsf = b2f[h] + (float)(g2[0] + g2[1]);
        float e2 = __builtin_amdgcn_exp2f(gsf * -1.44269504f);
        float sig = __builtin_amdgcn_rcpf(1.0f + e2);
        ov += fmaxf(acc[h][i], 0.0f) * sig;   // relu(dot_data+rpe) * gate
      }
      out[(size_t)(qb + wq * 16 + g * 4 + i) * NK + kb + krl] = ov;
    }
  }
}

// ---------------------------------------------------------------------------
extern "C" void kernel_launch(void* const* d_in, const int* in_sizes, int n_in,
                              void* d_out, int out_size, void* d_ws, size_t ws_size,
                              hipStream_t stream) {
  const float* Xq  = (const float*)d_in[0];
  const float* Xk  = (const float*)d_in[1];
  const int*   qpos = (const int*)d_in[2];
  const int*   kpos = (const int*)d_in[3];
  const float* Wq  = (const float*)d_in[4];
  const float* Wk  = (const float*)d_in[5];
  const float* rpe = (const float*)d_in[6];
  const float* gw1 = (const float*)d_in[7];
  const float* gb1 = (const float*)d_in[8];
  const float* gw2 = (const float*)d_in[9];
  const float* gb2 = (const float*)d_in[10];
  float* out = (float*)d_out;

  _Float16* qpf = (_Float16*)d_ws;                 // 2048*256 f16 = 1 MB
  _Float16* kpf = qpf + (size_t)NQ * HD;           // 4096*256 f16 = 2 MB

  proj_kernel<<<dim3(NQ / 32 + NK / 32, 8), 256, 0, stream>>>(
      Xq, Xk, Wq, Wk, qpf, kpf);
  fused_kernel<<<dim3(NK / 64, NQ / 32), 256, 0, stream>>>(
      qpf, kpf, qpos, kpos, rpe, gw1, gb1, gw2, gb2, out);
}

// Round 6
// 70.397 us; speedup vs baseline: 1.6135x; 1.0425x over previous
//
#include <hip/hip_runtime.h>
#include <hip/hip_fp16.h>

#define NQ 2048
#define NK 4096
#define DIMK 1024
#define HD 256          // 2*H*D_I
#define NBUCKET 257

typedef _Float16 h2 __attribute__((ext_vector_type(2)));
typedef _Float16 h4 __attribute__((ext_vector_type(4)));
typedef float f4 __attribute__((ext_vector_type(4)));

// v_cvt_pkrtz_f16_f32: pack two f32 into one f16x2 (bit-cast to our h2)
static __device__ __forceinline__ h2 cvt_pk(float a, float b) {
  return __builtin_bit_cast(h2, __builtin_amdgcn_cvt_pkrtz(a, b));
}

// async global->LDS, 16B per lane (size must be a literal)
#define GLDS16(gp, lp)                                              \
  __builtin_amdgcn_global_load_lds(                                 \
      (const __attribute__((address_space(1))) void*)(gp),          \
      (__attribute__((address_space(3))) void*)(lp), 16, 0, 0)

// ---------------------------------------------------------------------------
// Kernel 1: fused f32->f16 projection GEMM  P = X @ W^T  (f16 out)
// R2 config (measured ~15us): block tile 32(rows) x 64(cols), BK=64, 4 waves
// (2x2), wave tile 16x32 (8 MFMA per K-step). LDS 48 KB double-buffered,
// global_load_lds staging, source-side XOR swizzle (16B chunk ^= row&7).
// Grid.x = NQ/32 + NK/32 = 192, grid.y = 4.
// ---------------------------------------------------------------------------
__global__ __launch_bounds__(256) void proj_kernel(
    const float* __restrict__ Xq, const float* __restrict__ Xk,
    const float* __restrict__ Wq, const float* __restrict__ Wk,
    _Float16* __restrict__ Pq, _Float16* __restrict__ Pk)
{
  __shared__ __align__(16) float xs[2][32 * 64];   // 2 x 8 KB
  __shared__ __align__(16) float wsh[2][64 * 64];  // 2 x 16 KB -> 48 KB total

  const int t = threadIdx.x;
  const int lane = t & 63;
  const int wave = t >> 6;
  const int bx = blockIdx.x;
  const bool isq = bx < (NQ / 32);
  const float* __restrict__ X = isq ? Xq : Xk;
  const float* __restrict__ W = isq ? Wq : Wk;
  _Float16* __restrict__ P = isq ? Pq : Pk;
  const int rb = (isq ? bx : bx - NQ / 32) * 32;
  const int cb = blockIdx.y * 64;
  const int r15 = lane & 15, g = lane >> 4;
  const int wq = wave >> 1, wk = wave & 1;

  f4 acc[2];
  acc[0] = (f4){0.f, 0.f, 0.f, 0.f};
  acc[1] = (f4){0.f, 0.f, 0.f, 0.f};

  // stage one K-tile: X 2 calls + W 4 calls (each 256 lanes x 16B)
  auto stage = [&](int buf, int kb) {
#pragma unroll
    for (int j = 0; j < 2; ++j) {
      int chunk = j * 256 + t;              // 16B chunk in 32x64-float tile
      int row = chunk >> 4, c4 = chunk & 15;
      int gc = c4 ^ (row & 7);              // inverse-swizzled source chunk
      GLDS16(X + (size_t)(rb + row) * DIMK + kb + gc * 4, &xs[buf][chunk * 4]);
    }
#pragma unroll
    for (int j = 0; j < 4; ++j) {
      int chunk = j * 256 + t;              // 16B chunk in 64x64-float tile
      int row = chunk >> 4, c4 = chunk & 15;
      int gc = c4 ^ (row & 7);
      GLDS16(W + (size_t)(cb + row) * DIMK + kb + gc * 4, &wsh[buf][chunk * 4]);
    }
  };

  auto compute = [&](int buf) {
    const int arow = wq * 16 + r15;
#pragma unroll
    for (int kc = 0; kc < 4; ++kc) {
      int k4 = kc * 4 + g;                  // 16B chunk holding this frag's 4 vals
      f4 af = *(const f4*)&xs[buf][arow * 64 + ((k4 ^ (arow & 7)) << 2)];
      h2 alo = cvt_pk(af[0], af[1]);
      h2 ahi = cvt_pk(af[2], af[3]);
      h4 a = (h4){alo[0], alo[1], ahi[0], ahi[1]};
#pragma unroll
      for (int cs = 0; cs < 2; ++cs) {
        int brow = wk * 32 + cs * 16 + r15;
        f4 bf = *(const f4*)&wsh[buf][brow * 64 + ((k4 ^ (brow & 7)) << 2)];
        h2 blo = cvt_pk(bf[0], bf[1]);
        h2 bhi = cvt_pk(bf[2], bf[3]);
        h4 b = (h4){blo[0], blo[1], bhi[0], bhi[1]};
        acc[cs] = __builtin_amdgcn_mfma_f32_16x16x16f16(a, b, acc[cs], 0, 0, 0);
      }
    }
  };

  stage(0, 0);
  __syncthreads();
  int buf = 0;
  for (int tt = 0; tt < DIMK / 64; ++tt) {
    if (tt + 1 < DIMK / 64) stage(buf ^ 1, (tt + 1) * 64);
    compute(buf);
    __syncthreads();
    buf ^= 1;
  }

  // C/D layout: row = 4*(lane>>4)+i, col = lane&15  [measured m89]
#pragma unroll
  for (int cs = 0; cs < 2; ++cs)
#pragma unroll
    for (int i = 0; i < 4; ++i)
      P[(size_t)(rb + wq * 16 + g * 4 + i) * HD + cb + wk * 32 + cs * 16 + r15] =
          (_Float16)acc[cs][i];
}

// ---------------------------------------------------------------------------
// Kernel 2 (v4): k-tile in LDS (global_load_lds, swizzled source); q-strip
// register-resident (one-time scattered loads, hidden under staging); no
// position LDS. LDS = 36 KB -> 4 blocks/CU (16 waves). RPE preloaded into
// MFMA accumulator; packed-f16 gate MLP; sigmoid = exp2+rcp.
// Block 32q x 64k, 4 waves (2x2), wave 16q x 32k as two 16x16 k-subtiles.
// grid = (NK/64, NQ/32).
// ---------------------------------------------------------------------------
__global__ __launch_bounds__(256, 4) void fused_kernel(
    const _Float16* __restrict__ qp, const _Float16* __restrict__ kp,
    const int* __restrict__ qpos, const int* __restrict__ kpos,
    const float* __restrict__ rpe, const float* __restrict__ gw1,
    const float* __restrict__ gb1, const float* __restrict__ gw2,
    const float* __restrict__ gb2, float* __restrict__ out)
{
  __shared__ __align__(16) _Float16 klds[64 * 256];   // 32 KB
  __shared__ __align__(16) float rpel[NBUCKET * 4];   // 4112 B

  const int t = threadIdx.x;
  const int lane = t & 63, wave = t >> 6;
  const int wq = wave >> 1, wk = wave & 1;
  const int qb = blockIdx.y * 32, kb = blockIdx.x * 64;
  const int r15 = lane & 15, g = lane >> 4;

  // stage k tile: 64 rows x 256 halfs; source pre-swizzled so LDS half
  // index = colh ^ ((row&7)<<3)
#pragma unroll
  for (int j = 0; j < 8; ++j) {
    int chunk = j * 256 + t;
    int row = chunk >> 5, c = chunk & 31;
    GLDS16(kp + (size_t)(kb + row) * HD + (c ^ (row & 7)) * 8, &klds[chunk * 8]);
  }
  for (int i = t; i < NBUCKET * 4; i += 256) rpel[i] = rpe[i];

  // ---- A fragments (this wave's 16 q-rows) straight from global (L2) ----
  const int qrow = qb + wq * 16 + r15;
  const _Float16* qbase = qp + (size_t)qrow * HD + g * 4;
  h4 afr[8][2];
#pragma unroll
  for (int h = 0; h < 8; ++h)
#pragma unroll
    for (int c = 0; c < 2; ++c)
      afr[h][c] = *(const h4*)(qbase + h * 32 + c * 16);

  // per-lane positions (L2-served)
  const int4 qp4 = *(const int4*)(qpos + qb + wq * 16 + g * 4);
  int kpv2[2];
#pragma unroll
  for (int s = 0; s < 2; ++s) kpv2[s] = kpos[kb + wk * 32 + s * 16 + r15];

  // ---- packed-f16 gate weights (wave-uniform) ----
  h2 w1p[4][4], b1p[4];     // layer1: [head][hidden-pair]
  h2 w2hp[4][4];            // layer2: [head][hidden-pair]
  float b2f[4];
#pragma unroll
  for (int j = 0; j < 4; ++j) {
    b1p[j] = (h2){(_Float16)gb1[2 * j], (_Float16)gb1[2 * j + 1]};
#pragma unroll
    for (int h = 0; h < 4; ++h)
      w1p[h][j] = (h2){(_Float16)gw1[(2 * j) * 4 + h],
                       (_Float16)gw1[(2 * j + 1) * 4 + h]};
  }
#pragma unroll
  for (int h = 0; h < 4; ++h) {
    b2f[h] = gb2[h];
#pragma unroll
    for (int j = 0; j < 4; ++j)
      w2hp[h][j] = (h2){(_Float16)gw2[h * 8 + 2 * j],
                        (_Float16)gw2[h * 8 + 2 * j + 1]};
  }

  __syncthreads();   // klds + rpel ready (drains GLDS vmcnt)

  const int swz = (r15 & 7) << 3;   // half-index XOR for this lane's k-rows

#pragma unroll
  for (int s = 0; s < 2; ++s) {
    const int krl = wk * 32 + s * 16 + r15;   // k row within tile
    const int kpv = kpv2[s];

    // rpe gather for this lane's 4 output elements; preload into accumulator
    f4 rpv[4];
#pragma unroll
    for (int i = 0; i < 4; ++i) {
      int rel = qp4[i] - kpv;
      int bidx = (rel < -128 ? -128 : (rel > 128 ? 128 : rel)) + 128;
      rpv[i] = *(const f4*)&rpel[bidx * 4];
    }
    f4 acc[8];
#pragma unroll
    for (int h = 0; h < 8; ++h)
#pragma unroll
      for (int i = 0; i < 4; ++i) acc[h][i] = rpv[i][h & 3];

#pragma unroll
    for (int h = 0; h < 8; ++h)
#pragma unroll
      for (int c = 0; c < 2; ++c) {
        h4 b = *(const h4*)&klds[krl * 256 + ((h * 32 + c * 16 + g * 4) ^ swz)];
        acc[h] = __builtin_amdgcn_mfma_f32_16x16x16f16(afr[h][c], b, acc[h], 0, 0, 0);
      }

#pragma unroll
    for (int i = 0; i < 4; ++i) {
      // gate input (already includes rpe), packed to f16
      h2 gi01 = cvt_pk(acc[4][i], acc[5][i]);
      h2 gi23 = cvt_pk(acc[6][i], acc[7][i]);
      h2 s0 = __builtin_shufflevector(gi01, gi01, 0, 0);
      h2 s1 = __builtin_shufflevector(gi01, gi01, 1, 1);
      h2 s2 = __builtin_shufflevector(gi23, gi23, 0, 0);
      h2 s3 = __builtin_shufflevector(gi23, gi23, 1, 1);

      // layer 1: hidden pairs
      h2 hidp[4];
#pragma unroll
      for (int j = 0; j < 4; ++j) {
        h2 a = b1p[j];
        a += s0 * w1p[0][j];
        a += s1 * w1p[1][j];
        a += s2 * w1p[2][j];
        a += s3 * w1p[3][j];
        hidp[j] = __builtin_elementwise_max(a, (h2)(_Float16)0.0f);
      }

      float ov = 0.0f;
#pragma unroll
      for (int h = 0; h < 4; ++h) {
        h2 g2 = hidp[0] * w2hp[h][0];
        g2 += hidp[1] * w2hp[h][1];
        g2 += hidp[2] * w2hp[h][2];
        g2 += hidp[3] * w2hp[h][3];
        float gsf = b2f[h] + (float)(g2[0] + g2[1]);
        float e2 = __builtin_amdgcn_exp2f(gsf * -1.44269504f);
        float sig = __builtin_amdgcn_rcpf(1.0f + e2);
        ov += fmaxf(acc[h][i], 0.0f) * sig;   // relu(dot_data+rpe) * gate
      }
      out[(size_t)(qb + wq * 16 + g * 4 + i) * NK + kb + krl] = ov;
    }
  }
}

// ---------------------------------------------------------------------------
extern "C" void kernel_launch(void* const* d_in, const int* in_sizes, int n_in,
                              void* d_out, int out_size, void* d_ws, size_t ws_size,
                              hipStream_t stream) {
  const float* Xq  = (const float*)d_in[0];
  const float* Xk  = (const float*)d_in[1];
  const int*   qpos = (const int*)d_in[2];
  const int*   kpos = (const int*)d_in[3];
  const float* Wq  = (const float*)d_in[4];
  const float* Wk  = (const float*)d_in[5];
  const float* rpe = (const float*)d_in[6];
  const float* gw1 = (const float*)d_in[7];
  const float* gb1 = (const float*)d_in[8];
  const float* gw2 = (const float*)d_in[9];
  const float* gb2 = (const float*)d_in[10];
  float* out = (float*)d_out;

  _Float16* qpf = (_Float16*)d_ws;                 // 2048*256 f16 = 1 MB
  _Float16* kpf = qpf + (size_t)NQ * HD;           // 4096*256 f16 = 2 MB

  proj_kernel<<<dim3(NQ / 32 + NK / 32, 4), 256, 0, stream>>>(
      Xq, Xk, Wq, Wk, qpf, kpf);
  fused_kernel<<<dim3(NK / 64, NQ / 32), 256, 0, stream>>>(
      qpf, kpf, qpos, kpos, rpe, gw1, gb1, gw2, gb2, out);
}

// Round 7
// 63.372 us; speedup vs baseline: 1.7924x; 1.1109x over previous
//
#include <hip/hip_runtime.h>
#include <hip/hip_fp16.h>

#define NQ 2048
#define NK 4096
#define DIMK 1024
#define HD 256          // 2*H*D_I
#define NBUCKET 257
#define KCHUNK 64
#define KITER 8         // k-tiles per block
#define KSPAN (KCHUNK * KITER)   // 512

typedef _Float16 h2 __attribute__((ext_vector_type(2)));
typedef _Float16 h4 __attribute__((ext_vector_type(4)));
typedef float f4 __attribute__((ext_vector_type(4)));

// v_cvt_pkrtz_f16_f32: pack two f32 into one f16x2 (bit-cast to our h2)
static __device__ __forceinline__ h2 cvt_pk(float a, float b) {
  return __builtin_bit_cast(h2, __builtin_amdgcn_cvt_pkrtz(a, b));
}

// async global->LDS, 16B per lane (size must be a literal)
#define GLDS16(gp, lp)                                              \
  __builtin_amdgcn_global_load_lds(                                 \
      (const __attribute__((address_space(1))) void*)(gp),          \
      (__attribute__((address_space(3))) void*)(lp), 16, 0, 0)

// ---------------------------------------------------------------------------
// Kernel 1: fused f32->f16 projection GEMM  P = X @ W^T  (f16 out)
// R2 config (~15us): block tile 32 x 64, BK=64, 4 waves (2x2), wave 16x32.
// LDS 48 KB double-buffered, global_load_lds staging, source-side XOR swizzle.
// ---------------------------------------------------------------------------
__global__ __launch_bounds__(256) void proj_kernel(
    const float* __restrict__ Xq, const float* __restrict__ Xk,
    const float* __restrict__ Wq, const float* __restrict__ Wk,
    _Float16* __restrict__ Pq, _Float16* __restrict__ Pk)
{
  __shared__ __align__(16) float xs[2][32 * 64];   // 2 x 8 KB
  __shared__ __align__(16) float wsh[2][64 * 64];  // 2 x 16 KB -> 48 KB total

  const int t = threadIdx.x;
  const int lane = t & 63;
  const int wave = t >> 6;
  const int bx = blockIdx.x;
  const bool isq = bx < (NQ / 32);
  const float* __restrict__ X = isq ? Xq : Xk;
  const float* __restrict__ W = isq ? Wq : Wk;
  _Float16* __restrict__ P = isq ? Pq : Pk;
  const int rb = (isq ? bx : bx - NQ / 32) * 32;
  const int cb = blockIdx.y * 64;
  const int r15 = lane & 15, g = lane >> 4;
  const int wq = wave >> 1, wk = wave & 1;

  f4 acc[2];
  acc[0] = (f4){0.f, 0.f, 0.f, 0.f};
  acc[1] = (f4){0.f, 0.f, 0.f, 0.f};

  auto stage = [&](int buf, int kb) {
#pragma unroll
    for (int j = 0; j < 2; ++j) {
      int chunk = j * 256 + t;              // 16B chunk in 32x64-float tile
      int row = chunk >> 4, c4 = chunk & 15;
      int gc = c4 ^ (row & 7);              // inverse-swizzled source chunk
      GLDS16(X + (size_t)(rb + row) * DIMK + kb + gc * 4, &xs[buf][chunk * 4]);
    }
#pragma unroll
    for (int j = 0; j < 4; ++j) {
      int chunk = j * 256 + t;              // 16B chunk in 64x64-float tile
      int row = chunk >> 4, c4 = chunk & 15;
      int gc = c4 ^ (row & 7);
      GLDS16(W + (size_t)(cb + row) * DIMK + kb + gc * 4, &wsh[buf][chunk * 4]);
    }
  };

  auto compute = [&](int buf) {
    const int arow = wq * 16 + r15;
#pragma unroll
    for (int kc = 0; kc < 4; ++kc) {
      int k4 = kc * 4 + g;                  // 16B chunk holding this frag's 4 vals
      f4 af = *(const f4*)&xs[buf][arow * 64 + ((k4 ^ (arow & 7)) << 2)];
      h2 alo = cvt_pk(af[0], af[1]);
      h2 ahi = cvt_pk(af[2], af[3]);
      h4 a = (h4){alo[0], alo[1], ahi[0], ahi[1]};
#pragma unroll
      for (int cs = 0; cs < 2; ++cs) {
        int brow = wk * 32 + cs * 16 + r15;
        f4 bf = *(const f4*)&wsh[buf][brow * 64 + ((k4 ^ (brow & 7)) << 2)];
        h2 blo = cvt_pk(bf[0], bf[1]);
        h2 bhi = cvt_pk(bf[2], bf[3]);
        h4 b = (h4){blo[0], blo[1], bhi[0], bhi[1]};
        acc[cs] = __builtin_amdgcn_mfma_f32_16x16x16f16(a, b, acc[cs], 0, 0, 0);
      }
    }
  };

  stage(0, 0);
  __syncthreads();
  int buf = 0;
  for (int tt = 0; tt < DIMK / 64; ++tt) {
    if (tt + 1 < DIMK / 64) stage(buf ^ 1, (tt + 1) * 64);
    compute(buf);
    __syncthreads();
    buf ^= 1;
  }

  // C/D layout: row = 4*(lane>>4)+i, col = lane&15  [measured m89]
#pragma unroll
  for (int cs = 0; cs < 2; ++cs)
#pragma unroll
    for (int i = 0; i < 4; ++i)
      P[(size_t)(rb + wq * 16 + g * 4 + i) * HD + cb + wk * 32 + cs * 16 + r15] =
          (_Float16)acc[cs][i];
}

// ---------------------------------------------------------------------------
// Kernel 2 (v5): k-loop blocks. Each block owns a 32-q strip and iterates
// over 8 k-tiles of 64 (KSPAN=512 cols). q-frags, positions, rpe table and
// packed-f16 gate weights loaded ONCE per block (amortized 8x). k-tiles
// double-buffered via global_load_lds (swizzled source); staging of tile
// t+1 overlaps MFMA+epilogue of tile t; one barrier per iteration.
// grid = (NK/512, NQ/32) = (8, 64) = 512 blocks = 2/CU.
// ---------------------------------------------------------------------------
__global__ __launch_bounds__(256, 2) void fused_kernel(
    const _Float16* __restrict__ qp, const _Float16* __restrict__ kp,
    const int* __restrict__ qpos, const int* __restrict__ kpos,
    const float* __restrict__ rpe, const float* __restrict__ gw1,
    const float* __restrict__ gb1, const float* __restrict__ gw2,
    const float* __restrict__ gb2, float* __restrict__ out)
{
  __shared__ __align__(16) _Float16 klds[2][64 * 256];  // 2 x 32 KB
  __shared__ __align__(16) float rpel[NBUCKET * 4];     // 4112 B

  const int t = threadIdx.x;
  const int lane = t & 63, wave = t >> 6;
  const int wq = wave >> 1, wk = wave & 1;
  const int qb = blockIdx.y * 32;
  const int kb0 = blockIdx.x * KSPAN;
  const int r15 = lane & 15, g = lane >> 4;

  // stage one 64-row k-tile into buf; source pre-swizzled so LDS half
  // index = colh ^ ((row&7)<<3)
  auto stage = [&](int buf, int kb) {
#pragma unroll
    for (int j = 0; j < 8; ++j) {
      int chunk = j * 256 + t;
      int row = chunk >> 5, c = chunk & 31;
      GLDS16(kp + (size_t)(kb + row) * HD + (c ^ (row & 7)) * 8,
             &klds[buf][chunk * 8]);
    }
  };

  stage(0, kb0);
  for (int i = t; i < NBUCKET * 4; i += 256) rpel[i] = rpe[i];

  // ---- A fragments (this wave's 16 q-rows) straight from global (L2) ----
  const int qrow = qb + wq * 16 + r15;
  const _Float16* qbase = qp + (size_t)qrow * HD + g * 4;
  h4 afr[8][2];
#pragma unroll
  for (int h = 0; h < 8; ++h)
#pragma unroll
    for (int c = 0; c < 2; ++c)
      afr[h][c] = *(const h4*)(qbase + h * 32 + c * 16);

  const int4 qp4 = *(const int4*)(qpos + qb + wq * 16 + g * 4);

  // ---- packed-f16 gate weights (wave-uniform, once per block) ----
  h2 w1p[4][4], b1p[4];     // layer1: [head][hidden-pair]
  h2 w2hp[4][4];            // layer2: [head][hidden-pair]
  float b2f[4];
#pragma unroll
  for (int j = 0; j < 4; ++j) {
    b1p[j] = (h2){(_Float16)gb1[2 * j], (_Float16)gb1[2 * j + 1]};
#pragma unroll
    for (int h = 0; h < 4; ++h)
      w1p[h][j] = (h2){(_Float16)gw1[(2 * j) * 4 + h],
                       (_Float16)gw1[(2 * j + 1) * 4 + h]};
  }
#pragma unroll
  for (int h = 0; h < 4; ++h) {
    b2f[h] = gb2[h];
#pragma unroll
    for (int j = 0; j < 4; ++j)
      w2hp[h][j] = (h2){(_Float16)gw2[h * 8 + 2 * j],
                        (_Float16)gw2[h * 8 + 2 * j + 1]};
  }

  const int swz = (r15 & 7) << 3;   // half-index XOR for this lane's k-rows

  __syncthreads();   // first k-tile + rpel ready (drains GLDS vmcnt)

  int buf = 0;
  for (int tt = 0; tt < KITER; ++tt) {
    const int kb = kb0 + tt * KCHUNK;
    if (tt + 1 < KITER) stage(buf ^ 1, kb + KCHUNK);

    // per-lane k positions for both 16-row subtiles (L2-served, issued early)
    int kpv2[2];
#pragma unroll
    for (int s = 0; s < 2; ++s) kpv2[s] = kpos[kb + wk * 32 + s * 16 + r15];

#pragma unroll
    for (int s = 0; s < 2; ++s) {
      const int krl = wk * 32 + s * 16 + r15;   // k row within tile
      const int kpv = kpv2[s];

      // rpe gather for this lane's 4 output rows; preload into accumulator
      f4 rpv[4];
#pragma unroll
      for (int i = 0; i < 4; ++i) {
        int rel = qp4[i] - kpv;
        int bidx = (rel < -128 ? -128 : (rel > 128 ? 128 : rel)) + 128;
        rpv[i] = *(const f4*)&rpel[bidx * 4];
      }
      f4 acc[8];
#pragma unroll
      for (int h = 0; h < 8; ++h)
#pragma unroll
        for (int i = 0; i < 4; ++i) acc[h][i] = rpv[i][h & 3];

#pragma unroll
      for (int h = 0; h < 8; ++h)
#pragma unroll
        for (int c = 0; c < 2; ++c) {
          h4 b = *(const h4*)&klds[buf][krl * 256 +
                                        ((h * 32 + c * 16 + g * 4) ^ swz)];
          acc[h] =
              __builtin_amdgcn_mfma_f32_16x16x16f16(afr[h][c], b, acc[h], 0, 0, 0);
        }

#pragma unroll
      for (int i = 0; i < 4; ++i) {
        // gate input (already includes rpe), packed to f16
        h2 gi01 = cvt_pk(acc[4][i], acc[5][i]);
        h2 gi23 = cvt_pk(acc[6][i], acc[7][i]);
        h2 s0 = __builtin_shufflevector(gi01, gi01, 0, 0);
        h2 s1 = __builtin_shufflevector(gi01, gi01, 1, 1);
        h2 s2 = __builtin_shufflevector(gi23, gi23, 0, 0);
        h2 s3 = __builtin_shufflevector(gi23, gi23, 1, 1);

        // layer 1: hidden pairs
        h2 hidp[4];
#pragma unroll
        for (int j = 0; j < 4; ++j) {
          h2 a = b1p[j];
          a += s0 * w1p[0][j];
          a += s1 * w1p[1][j];
          a += s2 * w1p[2][j];
          a += s3 * w1p[3][j];
          hidp[j] = __builtin_elementwise_max(a, (h2)(_Float16)0.0f);
        }

        float ov = 0.0f;
#pragma unroll
        for (int h = 0; h < 4; ++h) {
          h2 g2 = hidp[0] * w2hp[h][0];
          g2 += hidp[1] * w2hp[h][1];
          g2 += hidp[2] * w2hp[h][2];
          g2 += hidp[3] * w2hp[h][3];
          float gsf = b2f[h] + (float)(g2[0] + g2[1]);
          float e2 = __builtin_amdgcn_exp2f(gsf * -1.44269504f);
          float sig = __builtin_amdgcn_rcpf(1.0f + e2);
          ov += fmaxf(acc[h][i], 0.0f) * sig;   // relu(dot_data+rpe) * gate
        }
        out[(size_t)(qb + wq * 16 + g * 4 + i) * NK + kb + krl] = ov;
      }
    }
    __syncthreads();
    buf ^= 1;
  }
}

// ---------------------------------------------------------------------------
extern "C" void kernel_launch(void* const* d_in, const int* in_sizes, int n_in,
                              void* d_out, int out_size, void* d_ws, size_t ws_size,
                              hipStream_t stream) {
  const float* Xq  = (const float*)d_in[0];
  const float* Xk  = (const float*)d_in[1];
  const int*   qpos = (const int*)d_in[2];
  const int*   kpos = (const int*)d_in[3];
  const float* Wq  = (const float*)d_in[4];
  const float* Wk  = (const float*)d_in[5];
  const float* rpe = (const float*)d_in[6];
  const float* gw1 = (const float*)d_in[7];
  const float* gb1 = (const float*)d_in[8];
  const float* gw2 = (const float*)d_in[9];
  const float* gb2 = (const float*)d_in[10];
  float* out = (float*)d_out;

  _Float16* qpf = (_Float16*)d_ws;                 // 2048*256 f16 = 1 MB
  _Float16* kpf = qpf + (size_t)NQ * HD;           // 4096*256 f16 = 2 MB

  proj_kernel<<<dim3(NQ / 32 + NK / 32, 4), 256, 0, stream>>>(
      Xq, Xk, Wq, Wk, qpf, kpf);
  fused_kernel<<<dim3(NK / KSPAN, NQ / 32), 256, 0, stream>>>(
      qpf, kpf, qpos, kpos, rpe, gw1, gb1, gw2, gb2, out);
}